// Round 1
// baseline (431.839 us; speedup 1.0000x reference)
//
#include <hip/hip_runtime.h>

#define B_TOT 262144
#define HID   256
#define NHEAD 8
#define BR    128      // rows per block
#define NTHR  512      // 8 waves

typedef __bf16 bf16_t;
typedef __attribute__((ext_vector_type(8))) __bf16 bf16x8;
typedef __attribute__((ext_vector_type(4))) __bf16 bf16x4;
typedef __attribute__((ext_vector_type(4))) float  f32x4;

static __device__ __forceinline__ f32x4 mfma16(bf16x8 a, bf16x8 b, f32x4 c) {
  return __builtin_amdgcn_mfma_f32_16x16x32_bf16(a, b, c, 0, 0, 0);
}

static __device__ __forceinline__ bf16x8 cvt8(float4 a, float4 b) {
  bf16x8 r;
  r[0] = (bf16_t)a.x; r[1] = (bf16_t)a.y; r[2] = (bf16_t)a.z; r[3] = (bf16_t)a.w;
  r[4] = (bf16_t)b.x; r[5] = (bf16_t)b.y; r[6] = (bf16_t)b.z; r[7] = (bf16_t)b.w;
  return r;
}

// load the f32 W-slices for head h into registers (cooperative, 512 threads)
static __device__ __forceinline__ void load_w(const float* __restrict__ Wq,
                                              const float* __restrict__ Wk,
                                              const float* __restrict__ Wv,
                                              int h, int tid, float4 (&wr)[12]) {
#pragma unroll
  for (int i = 0; i < 2; ++i) {
    const int chunk = tid + i * 512;          // 0..1023
    const int rrow  = chunk >> 5;             // 0..31 (row within slice)
    const int ccol  = (chunk & 31) * 8;       // 0..248
    const size_t g  = (size_t)(h * 32 + rrow) * HID + ccol;
    wr[0 + i * 2 + 0] = *(const float4*)(Wq + g);
    wr[0 + i * 2 + 1] = *(const float4*)(Wq + g + 4);
    wr[4 + i * 2 + 0] = *(const float4*)(Wk + g);
    wr[4 + i * 2 + 1] = *(const float4*)(Wk + g + 4);
    wr[8 + i * 2 + 0] = *(const float4*)(Wv + g);
    wr[8 + i * 2 + 1] = *(const float4*)(Wv + g + 4);
  }
}

// convert + store staged registers into swizzled LDS W-slice buffer
static __device__ __forceinline__ void store_w(char* wlds, int tid, float4 (&wr)[12]) {
#pragma unroll
  for (int i = 0; i < 2; ++i) {
    const int chunk = tid + i * 512;
    const int rrow  = chunk >> 5;
    const int ccol  = (chunk & 31) * 8;
    const int bofs  = rrow * 512 + ((ccol * 2) ^ ((rrow & 7) << 4));
    *(bf16x8*)(wlds +     0 + bofs) = cvt8(wr[0 + i * 2 + 0], wr[0 + i * 2 + 1]);
    *(bf16x8*)(wlds + 16384 + bofs) = cvt8(wr[4 + i * 2 + 0], wr[4 + i * 2 + 1]);
    *(bf16x8*)(wlds + 32768 + bofs) = cvt8(wr[8 + i * 2 + 0], wr[8 + i * 2 + 1]);
  }
}

__global__ __launch_bounds__(NTHR, 2) void fused_local_aug(
    const float* __restrict__ fine, const float* __restrict__ coarse,
    const float* __restrict__ motif, const float* __restrict__ Wq,
    const float* __restrict__ Wk, const float* __restrict__ Wv,
    const float* __restrict__ Wo, const float* __restrict__ bo,
    float* __restrict__ out) {
  __shared__ char smem[114688];
  char* wlds = smem;           // 3 * 32 * 256 bf16 = 48 KB (per-head W slices)
  char* mlds = smem + 49152;   // 128 * 256 bf16 = 64 KB (attention output "mid")

  const int tid  = threadIdx.x;
  const int lane = tid & 63;
  const int wave = tid >> 6;        // 0..7
  const int l15  = lane & 15;
  const int lg   = lane >> 4;       // 0..3
  const size_t row0 = (size_t)blockIdx.x * BR;
  const int    mrow = (int)row0 + wave * 16 + l15;   // this lane's batch row

  // ---- preload this wave's 16 X rows into bf16 register fragments ----
  bf16x8 xm[8], xf[8], xc[8];
  {
    const float* pm = motif  + (size_t)mrow * HID + lg * 8;
    const float* pf = fine   + (size_t)mrow * HID + lg * 8;
    const float* pc = coarse + (size_t)mrow * HID + lg * 8;
#pragma unroll
    for (int s = 0; s < 8; ++s) {
      xm[s] = cvt8(*(const float4*)(pm + s * 32), *(const float4*)(pm + s * 32 + 4));
      xf[s] = cvt8(*(const float4*)(pf + s * 32), *(const float4*)(pf + s * 32 + 4));
      xc[s] = cvt8(*(const float4*)(pc + s * 32), *(const float4*)(pc + s * 32 + 4));
    }
  }

  float4 wr[12];
  load_w(Wq, Wk, Wv, 0, tid, wr);

  const int m_l = wave * 16 + l15;       // mid row this lane owns
  const int msw = (l15 & 7) << 4;        // swizzle for that row (m&7 == l15&7)

#pragma unroll 1
  for (int h = 0; h < NHEAD; ++h) {
    __syncthreads();                 // prior head's LDS reads complete
    store_w(wlds, tid, wr);          // waits vmcnt, cvt, ds_write
    __syncthreads();                 // slice visible
    if (h < NHEAD - 1) load_w(Wq, Wk, Wv, h + 1, tid, wr);  // overlap w/ compute

    f32x4 aQ0{}, aQ1{}, aK10{}, aK11{}, aK20{}, aK21{}, aV10{}, aV11{}, aV20{}, aV21{};
    const int rb0 = l15 * 512;
    const int rb1 = (16 + l15) * 512;
    const int rsw = (l15 & 7) << 4;
#pragma unroll
    for (int ks = 0; ks < 8; ++ks) {
      const int kb = (ks * 64 + lg * 16) ^ rsw;
      bf16x8 q0 = *(const bf16x8*)(wlds +         rb0 + kb);
      bf16x8 q1 = *(const bf16x8*)(wlds +         rb1 + kb);
      bf16x8 k0 = *(const bf16x8*)(wlds + 16384 + rb0 + kb);
      bf16x8 k1 = *(const bf16x8*)(wlds + 16384 + rb1 + kb);
      bf16x8 v0 = *(const bf16x8*)(wlds + 32768 + rb0 + kb);
      bf16x8 v1 = *(const bf16x8*)(wlds + 32768 + rb1 + kb);
      aQ0  = mfma16(q0, xm[ks], aQ0);   aQ1  = mfma16(q1, xm[ks], aQ1);
      aK10 = mfma16(k0, xf[ks], aK10);  aK11 = mfma16(k1, xf[ks], aK11);
      aK20 = mfma16(k0, xc[ks], aK20);  aK21 = mfma16(k1, xc[ks], aK21);
      aV10 = mfma16(v0, xf[ks], aV10);  aV11 = mfma16(v1, xf[ks], aV11);
      aV20 = mfma16(v0, xc[ks], aV20);  aV21 = mfma16(v1, xc[ks], aV21);
    }
    // scores: per-lane partial over (tile, reg), then reduce across lane>>4 groups
    float s1 = 0.f, s2 = 0.f;
#pragma unroll
    for (int r = 0; r < 4; ++r) {
      s1 += aQ0[r] * aK10[r] + aQ1[r] * aK11[r];
      s2 += aQ0[r] * aK20[r] + aQ1[r] * aK21[r];
    }
    s1 += __shfl_xor(s1, 16); s1 += __shfl_xor(s1, 32);
    s2 += __shfl_xor(s2, 16); s2 += __shfl_xor(s2, 32);
    s1 *= (1.0f / 32.0f);  s2 *= (1.0f / 32.0f);   // reference divides by d_k
    const float mx = fmaxf(s1, s2);
    const float e1 = __expf(s1 - mx), e2 = __expf(s2 - mx);
    const float a1 = e1 / (e1 + e2);
    const float a2 = 1.0f - a1;
    // attention mix in fragment registers, write bf16 mid to LDS
    bf16x4 o0, o1;
#pragma unroll
    for (int r = 0; r < 4; ++r) {
      o0[r] = (bf16_t)(a1 * aV10[r] + a2 * aV20[r]);
      o1[r] = (bf16_t)(a1 * aV11[r] + a2 * aV21[r]);
    }
    const int n0 = h * 32 + lg * 4;
    *(bf16x4*)(mlds + m_l * 512 + ((n0 * 2)        ^ msw)) = o0;
    *(bf16x4*)(mlds + m_l * 512 + (((n0 + 16) * 2) ^ msw)) = o1;
  }
  __syncthreads();   // mid complete, all waves may read all rows

  // ---- output projection: out^T = Wo @ mid^T ; wave owns 32 output cols ----
  f32x4 acc[2][8];
#pragma unroll
  for (int jt = 0; jt < 2; ++jt)
#pragma unroll
    for (int mt = 0; mt < 8; ++mt) acc[jt][mt] = f32x4{0.f, 0.f, 0.f, 0.f};

  const int j0 = wave * 32;
  for (int ks = 0; ks < 8; ++ks) {
    bf16x8 wf0, wf1;
    {
      const float* p0 = Wo + (size_t)(j0 + l15) * HID + ks * 32 + lg * 8;
      const float* p1 = p0 + 16 * HID;
      wf0 = cvt8(*(const float4*)p0, *(const float4*)(p0 + 4));
      wf1 = cvt8(*(const float4*)p1, *(const float4*)(p1 + 4));
    }
    const int kb = ks * 64 + lg * 16;
#pragma unroll
    for (int mt = 0; mt < 8; ++mt) {
      const int m = mt * 16 + l15;
      bf16x8 mf = *(const bf16x8*)(mlds + m * 512 + (kb ^ msw));
      acc[0][mt] = mfma16(wf0, mf, acc[0][mt]);
      acc[1][mt] = mfma16(wf1, mf, acc[1][mt]);
    }
  }

  // epilogue: add bias, store float4 (4 consecutive j per lane)
#pragma unroll
  for (int jt = 0; jt < 2; ++jt) {
    const int jj = j0 + jt * 16 + lg * 4;
    const float4 b4 = *(const float4*)(bo + jj);
#pragma unroll
    for (int mt = 0; mt < 8; ++mt) {
      const int m = mt * 16 + l15;
      float4 o;
      o.x = acc[jt][mt][0] + b4.x;
      o.y = acc[jt][mt][1] + b4.y;
      o.z = acc[jt][mt][2] + b4.z;
      o.w = acc[jt][mt][3] + b4.w;
      *(float4*)(out + (row0 + m) * HID + jj) = o;
    }
  }
}

extern "C" void kernel_launch(void* const* d_in, const int* in_sizes, int n_in,
                              void* d_out, int out_size, void* d_ws, size_t ws_size,
                              hipStream_t stream) {
  (void)in_sizes; (void)n_in; (void)d_ws; (void)ws_size; (void)out_size;
  const float* fine   = (const float*)d_in[0];
  const float* coarse = (const float*)d_in[1];
  const float* motif  = (const float*)d_in[2];
  const float* Wq     = (const float*)d_in[3];
  const float* Wk     = (const float*)d_in[4];
  const float* Wv     = (const float*)d_in[5];
  const float* Wo     = (const float*)d_in[6];
  const float* bo     = (const float*)d_in[7];
  float* out          = (float*)d_out;

  dim3 grid(B_TOT / BR);
  fused_local_aug<<<grid, NTHR, 0, stream>>>(fine, coarse, motif,
                                             Wq, Wk, Wv, Wo, bo, out);
}